// Round 1
// baseline (515.309 us; speedup 1.0000x reference)
//
#include <hip/hip_runtime.h>
#include <stdint.h>

#define T_LEN 200
#define B_SZ  1024
#define D_DIM 128
#define NTILE (T_LEN * B_SZ / 16)   // 12800 M-tiles of 16 batch-rows

typedef __bf16 bf16_t;
typedef __bf16 bf16x8 __attribute__((ext_vector_type(8)));
typedef float  f32x4  __attribute__((ext_vector_type(4)));

union BF8 { bf16x8 v; bf16_t e[8]; };

// RNE fp32->bf16 pack of two values into one dword
__device__ inline uint32_t pk_bf16(float a, float b) {
  uint32_t ua = __float_as_uint(a), ub = __float_as_uint(b);
  ua += 0x7fffu + ((ua >> 16) & 1u);
  ub += 0x7fffu + ((ub >> 16) & 1u);
  return (ua >> 16) | (ub & 0xffff0000u);
}
__device__ inline float lo_bf(uint32_t x) { return __uint_as_float(x << 16); }
__device__ inline float hi_bf(uint32_t x) { return __uint_as_float(x & 0xffff0000u); }
__device__ inline float sigm(float x)  { return 1.0f / (1.0f + __expf(-x)); }
__device__ inline float tanh_f(float x){ return 1.0f - 2.0f / (__expf(2.0f * x) + 1.0f); }

// ---------------------------------------------------------------------------
// K1: G[t,b,:] = x[t,b,:] @ [Wau|War|Wac] + [bau|bar|bac], stored bf16,
// pre-swizzled to the (tile, wave, lane) C-layout K2 consumes.
// Per (tile tau, wave w): 3 uint2 per lane at G + (tau*8+w)*192 + {0,64,128} + l
// pair p: p=0 -> u gate vals (i=0..3), p=1 -> r, p=2 -> c.
// ---------------------------------------------------------------------------
__global__ __launch_bounds__(512) void k1_gates(
    const float* __restrict__ x,
    const float* __restrict__ Wau, const float* __restrict__ bau,
    const float* __restrict__ War, const float* __restrict__ bar,
    const float* __restrict__ Wac, const float* __restrict__ bac,
    uint2* __restrict__ G)
{
  const int tid = threadIdx.x;
  const int w  = tid >> 6;
  const int l  = tid & 63;
  const int lm = l & 15;     // M index (batch row within tile) for A, N col for B/C
  const int lg = l >> 4;     // k-group
  const int col = w * 16 + lm;

  // B-fragments of the three x-side weights, held in registers for the whole kernel.
  BF8 bu[4], br[4], bc[4];
#pragma unroll
  for (int kk = 0; kk < 4; ++kk) {
#pragma unroll
    for (int j = 0; j < 8; ++j) {
      int k = kk * 32 + lg * 8 + j;
      bu[kk].e[j] = (bf16_t)Wau[k * 128 + col];
      br[kk].e[j] = (bf16_t)War[k * 128 + col];
      bc[kk].e[j] = (bf16_t)Wac[k * 128 + col];
    }
  }
  const float b_u = bau[col], b_r = bar[col], b_c = bac[col];

  for (int tau = blockIdx.x; tau < NTILE; tau += gridDim.x) {
    const int t  = tau >> 6;
    const int bb = tau & 63;
    const float* xp = x + (size_t)(t * B_SZ + bb * 16 + lm) * D_DIM + lg * 8;

    BF8 aF[4];
#pragma unroll
    for (int kk = 0; kk < 4; ++kk) {
      float4 f0 = *(const float4*)(xp + kk * 32);
      float4 f1 = *(const float4*)(xp + kk * 32 + 4);
      aF[kk].e[0] = (bf16_t)f0.x; aF[kk].e[1] = (bf16_t)f0.y;
      aF[kk].e[2] = (bf16_t)f0.z; aF[kk].e[3] = (bf16_t)f0.w;
      aF[kk].e[4] = (bf16_t)f1.x; aF[kk].e[5] = (bf16_t)f1.y;
      aF[kk].e[6] = (bf16_t)f1.z; aF[kk].e[7] = (bf16_t)f1.w;
    }

    f32x4 aU = {b_u, b_u, b_u, b_u};
    f32x4 aR = {b_r, b_r, b_r, b_r};
    f32x4 aC = {b_c, b_c, b_c, b_c};
#pragma unroll
    for (int kk = 0; kk < 4; ++kk) {
      aU = __builtin_amdgcn_mfma_f32_16x16x32_bf16(aF[kk].v, bu[kk].v, aU, 0, 0, 0);
      aR = __builtin_amdgcn_mfma_f32_16x16x32_bf16(aF[kk].v, br[kk].v, aR, 0, 0, 0);
      aC = __builtin_amdgcn_mfma_f32_16x16x32_bf16(aF[kk].v, bc[kk].v, aC, 0, 0, 0);
    }

    uint2* gp = G + ((size_t)tau * 8 + w) * 192 + l;
    gp[0]   = make_uint2(pk_bf16(aU[0], aU[1]), pk_bf16(aU[2], aU[3]));
    gp[64]  = make_uint2(pk_bf16(aR[0], aR[1]), pk_bf16(aR[2], aR[3]));
    gp[128] = make_uint2(pk_bf16(aC[0], aC[1]), pk_bf16(aC[2], aC[3]));
  }
}

// ---------------------------------------------------------------------------
// K2: sequential scan. 64 blocks x 512 threads; block bb owns batch rows
// [16*bb, 16*bb+16). Wb* B-fragments in registers; state fp32 in LDS with a
// bf16 ping-pong copy for MFMA A-fragments; 1 barrier/step; G prefetched
// one step ahead into registers.
// ---------------------------------------------------------------------------
__global__ __launch_bounds__(512) void k2_scan(
    const float* __restrict__ state,
    const float* __restrict__ att,
    const float* __restrict__ mask,
    const float* __restrict__ Wbu, const float* __restrict__ Wbr,
    const float* __restrict__ Wbc,
    const uint2* __restrict__ G,
    float* __restrict__ out)
{
  __shared__ float  s_f32[16 * 132];          // fp32 state, padded stride 132
  __shared__ bf16_t s_b16[2][16 * 136];       // bf16 state ping-pong, stride 136
  __shared__ float  a_lds[T_LEN * 16];        // att_score [t][row]
  __shared__ float  m_lds[16 * T_LEN];        // mask [row][t]

  const int tid = threadIdx.x;
  const int w  = tid >> 6;
  const int l  = tid & 63;
  const int lm = l & 15;
  const int lg = l >> 4;
  const int bb = blockIdx.x;
  const int R0 = bb * 16;
  const int col = w * 16 + lm;

  // Recurrent-weight B-fragments (registers, whole kernel)
  BF8 bu[4], br[4], bc[4];
#pragma unroll
  for (int kk = 0; kk < 4; ++kk) {
#pragma unroll
    for (int j = 0; j < 8; ++j) {
      int k = kk * 32 + lg * 8 + j;
      bu[kk].e[j] = (bf16_t)Wbu[k * 128 + col];
      br[kk].e[j] = (bf16_t)Wbr[k * 128 + col];
      bc[kk].e[j] = (bf16_t)Wbc[k * 128 + col];
    }
  }

  // Preload att (strided) and mask (contiguous) for this block's rows
  for (int idx = tid; idx < T_LEN * 16; idx += 512)
    a_lds[idx] = att[(idx >> 4) * B_SZ + R0 + (idx & 15)];
  for (int idx = tid; idx < 16 * T_LEN; idx += 512)
    m_lds[idx] = mask[R0 * T_LEN + idx];

  // Init state (fp32 + bf16 copy into buffer 0)
  for (int idx = tid; idx < 16 * 128; idx += 512) {
    int r = idx >> 7, c = idx & 127;
    float v = state[(R0 + r) * 128 + c];
    s_f32[r * 132 + c] = v;
    s_b16[0][r * 136 + c] = (bf16_t)v;
  }

  // Prefetch gates for t=0
  const uint2* gb0 = G + ((size_t)(0 * 64 + bb) * 8 + w) * 192 + l;
  uint2 g0 = gb0[0], g1 = gb0[64], g2 = gb0[128];

  __syncthreads();

  for (int t = 0; t < T_LEN; ++t) {
    // prefetch next step's gates (drained into regs by the end-of-step barrier)
    uint2 n0, n1, n2;
    if (t < T_LEN - 1) {
      const uint2* gn = G + ((size_t)((t + 1) * 64 + bb) * 8 + w) * 192 + l;
      n0 = gn[0]; n1 = gn[64]; n2 = gn[128];
    }

    const int rp = t & 1;
    bf16x8 aF[4];
#pragma unroll
    for (int kk = 0; kk < 4; ++kk)
      aF[kk] = *(const bf16x8*)&s_b16[rp][lm * 136 + kk * 32 + lg * 8];

    f32x4 aU = {0.f, 0.f, 0.f, 0.f};
    f32x4 aR = {0.f, 0.f, 0.f, 0.f};
    f32x4 aC = {0.f, 0.f, 0.f, 0.f};
#pragma unroll
    for (int kk = 0; kk < 4; ++kk) {
      aU = __builtin_amdgcn_mfma_f32_16x16x32_bf16(aF[kk], bu[kk].v, aU, 0, 0, 0);
      aR = __builtin_amdgcn_mfma_f32_16x16x32_bf16(aF[kk], br[kk].v, aR, 0, 0, 0);
      aC = __builtin_amdgcn_mfma_f32_16x16x32_bf16(aF[kk], bc[kk].v, aC, 0, 0, 0);
    }

    const float gu[4] = { lo_bf(g0.x), hi_bf(g0.x), lo_bf(g0.y), hi_bf(g0.y) };
    const float gr[4] = { lo_bf(g1.x), hi_bf(g1.x), lo_bf(g1.y), hi_bf(g1.y) };
    const float gc[4] = { lo_bf(g2.x), hi_bf(g2.x), lo_bf(g2.y), hi_bf(g2.y) };

#pragma unroll
    for (int i = 0; i < 4; ++i) {
      const int row = lg * 4 + i;
      float u = sigm(aU[i] + gu[i]);
      float r = sigm(aR[i] + gr[i]);
      float c = tanh_f(gc[i] + r * aC[i]);
      float at = a_lds[t * 16 + row];
      float mt = m_lds[row * T_LEN + t];
      float so = s_f32[row * 132 + col];
      float uu = at * u;
      float sn = so + uu * (c - so);       // (1-u_)*s + u_*c
      float sf = so + mt * (sn - so);      // mask blend
      s_f32[row * 132 + col] = sf;
      s_b16[rp ^ 1][row * 136 + col] = (bf16_t)sf;
    }

    g0 = n0; g1 = n1; g2 = n2;
    __syncthreads();
  }

  // Write final state
  for (int idx = tid; idx < 16 * 128; idx += 512) {
    int r = idx >> 7, c = idx & 127;
    out[(R0 + r) * 128 + c] = s_f32[r * 132 + c];
  }
}

// ---------------------------------------------------------------------------
extern "C" void kernel_launch(void* const* d_in, const int* in_sizes, int n_in,
                              void* d_out, int out_size, void* d_ws, size_t ws_size,
                              hipStream_t stream)
{
  const float* x    = (const float*)d_in[0];
  const float* st   = (const float*)d_in[1];
  const float* att  = (const float*)d_in[2];
  const float* mask = (const float*)d_in[3];
  // d_in[4] = max_len (unused; shapes hard-coded)
  const float* Wau  = (const float*)d_in[5];
  const float* bau  = (const float*)d_in[6];
  const float* Wbu  = (const float*)d_in[7];
  const float* War  = (const float*)d_in[8];
  const float* bar  = (const float*)d_in[9];
  const float* Wbr  = (const float*)d_in[10];
  const float* Wac  = (const float*)d_in[11];
  const float* bac  = (const float*)d_in[12];
  const float* Wbc  = (const float*)d_in[13];

  uint2* G = (uint2*)d_ws;  // needs 12800*8*192*8 = 157,286,400 bytes

  k1_gates<<<dim3(256), dim3(512), 0, stream>>>(x, Wau, bau, War, bar, Wac, bac, G);
  k2_scan<<<dim3(64), dim3(512), 0, stream>>>(st, att, mask, Wbu, Wbr, Wbc, G,
                                              (float*)d_out);
}

// Round 2
// 403.742 us; speedup vs baseline: 1.2763x; 1.2763x over previous
//
#include <hip/hip_runtime.h>
#include <stdint.h>

#define T_LEN 200
#define B_SZ  1024
#define D_DIM 128
#define NTILE (T_LEN * B_SZ / 16)   // 12800 M-tiles of 16 batch-rows

typedef __bf16 bf16_t;
typedef __bf16 bf16x8 __attribute__((ext_vector_type(8)));
typedef __bf16 bf16x4 __attribute__((ext_vector_type(4)));
typedef float  f32x4  __attribute__((ext_vector_type(4)));
typedef float  f32x8  __attribute__((ext_vector_type(8)));

union BF8 { bf16x8 v; bf16_t e[8]; };
union F8V { f32x8 v; float4 q[2]; };

// RNE fp32->bf16 pack of two values into one dword
__device__ inline uint32_t pk_bf16(float a, float b) {
  uint32_t ua = __float_as_uint(a), ub = __float_as_uint(b);
  ua += 0x7fffu + ((ua >> 16) & 1u);
  ub += 0x7fffu + ((ub >> 16) & 1u);
  return (ua >> 16) | (ub & 0xffff0000u);
}
__device__ inline float lo_bf(uint32_t x) { return __uint_as_float(x << 16); }
__device__ inline float hi_bf(uint32_t x) { return __uint_as_float(x & 0xffff0000u); }
__device__ inline float rcp_f(float x)  { return __builtin_amdgcn_rcpf(x); }
__device__ inline float sigm(float x)   { return rcp_f(1.0f + __expf(-x)); }
__device__ inline float tanh_f(float x) { return 1.0f - 2.0f * rcp_f(__expf(2.0f * x) + 1.0f); }

// LDS-only barrier: wait LDS ops, but leave global loads (vmcnt) in flight.
#define BAR_LDS() asm volatile("s_waitcnt lgkmcnt(0)\n\ts_barrier" ::: "memory")

// ---------------------------------------------------------------------------
// K1: G[t,b,:] = x[t,b,:] @ [Wau|War|Wac] + [bau|bar|bac], stored bf16,
// pre-swizzled to the (tile, wave, lane) C-layout K2 consumes.
// ---------------------------------------------------------------------------
__global__ __launch_bounds__(512) void k1_gates(
    const float* __restrict__ x,
    const float* __restrict__ Wau, const float* __restrict__ bau,
    const float* __restrict__ War, const float* __restrict__ bar,
    const float* __restrict__ Wac, const float* __restrict__ bac,
    uint2* __restrict__ G)
{
  const int tid = threadIdx.x;
  const int w  = tid >> 6;
  const int l  = tid & 63;
  const int lm = l & 15;
  const int lg = l >> 4;
  const int col = w * 16 + lm;

  BF8 bu[4], br[4], bc[4];
#pragma unroll
  for (int kk = 0; kk < 4; ++kk) {
#pragma unroll
    for (int j = 0; j < 8; ++j) {
      int k = kk * 32 + lg * 8 + j;
      bu[kk].e[j] = (bf16_t)Wau[k * 128 + col];
      br[kk].e[j] = (bf16_t)War[k * 128 + col];
      bc[kk].e[j] = (bf16_t)Wac[k * 128 + col];
    }
  }
  const float b_u = bau[col], b_r = bar[col], b_c = bac[col];

  for (int tau = blockIdx.x; tau < NTILE; tau += gridDim.x) {
    const int t  = tau >> 6;
    const int bb = tau & 63;
    const float* xp = x + (size_t)(t * B_SZ + bb * 16 + lm) * D_DIM + lg * 8;

    bf16x8 aF[4];
#pragma unroll
    for (int kk = 0; kk < 4; ++kk) {
      F8V t8;
      t8.q[0] = *(const float4*)(xp + kk * 32);
      t8.q[1] = *(const float4*)(xp + kk * 32 + 4);
      aF[kk] = __builtin_convertvector(t8.v, bf16x8);
    }

    f32x4 aU = {b_u, b_u, b_u, b_u};
    f32x4 aR = {b_r, b_r, b_r, b_r};
    f32x4 aC = {b_c, b_c, b_c, b_c};
#pragma unroll
    for (int kk = 0; kk < 4; ++kk) {
      aU = __builtin_amdgcn_mfma_f32_16x16x32_bf16(aF[kk], bu[kk].v, aU, 0, 0, 0);
      aR = __builtin_amdgcn_mfma_f32_16x16x32_bf16(aF[kk], br[kk].v, aR, 0, 0, 0);
      aC = __builtin_amdgcn_mfma_f32_16x16x32_bf16(aF[kk], bc[kk].v, aC, 0, 0, 0);
    }

    uint2* gp = G + ((size_t)tau * 8 + w) * 192 + l;
    gp[0]   = make_uint2(pk_bf16(aU[0], aU[1]), pk_bf16(aU[2], aU[3]));
    gp[64]  = make_uint2(pk_bf16(aR[0], aR[1]), pk_bf16(aR[2], aR[3]));
    gp[128] = make_uint2(pk_bf16(aC[0], aC[1]), pk_bf16(aC[2], aC[3]));
  }
}

// ---------------------------------------------------------------------------
// K2: sequential scan. 64 blocks x 512 threads; fp32 state in REGISTERS
// (each lane owns 4 (row,col) cells); bf16 state ping-pong in LDS for the
// cross-wave MFMA A-fragment exchange; LDS-only barrier (global prefetch
// stays in flight); G prefetched depth-2.
// ---------------------------------------------------------------------------
__global__ __launch_bounds__(512) void k2_scan(
    const float* __restrict__ state,
    const float* __restrict__ att,
    const float* __restrict__ mask,
    const float* __restrict__ Wbu, const float* __restrict__ Wbr,
    const float* __restrict__ Wbc,
    const uint2* __restrict__ G,
    float* __restrict__ out)
{
  __shared__ bf16_t s_b16[2][16 * 136];       // bf16 state ping-pong, stride 136
  __shared__ float  a_lds[T_LEN * 16];        // att_score [t][row]
  __shared__ float  m_lds[16 * T_LEN];        // mask [row][t]

  const int tid = threadIdx.x;
  const int w  = tid >> 6;
  const int l  = tid & 63;
  const int lm = l & 15;
  const int lg = l >> 4;
  const int bb = blockIdx.x;
  const int R0 = bb * 16;
  const int col = w * 16 + lm;

  // Recurrent-weight B-fragments (registers, whole kernel)
  BF8 bu[4], br[4], bc[4];
#pragma unroll
  for (int kk = 0; kk < 4; ++kk) {
#pragma unroll
    for (int j = 0; j < 8; ++j) {
      int k = kk * 32 + lg * 8 + j;
      bu[kk].e[j] = (bf16_t)Wbu[k * 128 + col];
      br[kk].e[j] = (bf16_t)Wbr[k * 128 + col];
      bc[kk].e[j] = (bf16_t)Wbc[k * 128 + col];
    }
  }

  // Preload att (strided) and mask (contiguous) for this block's rows
  for (int idx = tid; idx < T_LEN * 16; idx += 512)
    a_lds[idx] = att[(idx >> 4) * B_SZ + R0 + (idx & 15)];
  for (int idx = tid; idx < 16 * T_LEN; idx += 512)
    m_lds[idx] = mask[R0 * T_LEN + idx];

  // fp32 state in registers: lane owns (row = lg*4+i, col)
  float sreg[4];
#pragma unroll
  for (int i = 0; i < 4; ++i) {
    const int row = lg * 4 + i;
    sreg[i] = state[(R0 + row) * 128 + col];
    s_b16[0][row * 136 + col] = (bf16_t)sreg[i];
  }

  // Prefetch gates for t=0 and t=1 (depth-2)
  const uint2* g0p = G + ((size_t)(0 * 64 + bb) * 8 + w) * 192 + l;
  uint2 c0 = g0p[0], c1 = g0p[64], c2 = g0p[128];
  const uint2* g1p = G + ((size_t)(1 * 64 + bb) * 8 + w) * 192 + l;
  uint2 d0 = g1p[0], d1 = g1p[64], d2 = g1p[128];

  __syncthreads();   // one full sync before the scan (drains init stores/loads)

  auto step = [&](int t, uint2& q0, uint2& q1, uint2& q2) {
    // issue prefetch for t+2 (lands 2 barriers later; vmcnt NOT drained)
    const int tp = (t + 2 <= T_LEN - 1) ? t + 2 : T_LEN - 1;
    const uint2* gn = G + ((size_t)(tp * 64 + bb) * 8 + w) * 192 + l;
    uint2 p0 = gn[0], p1 = gn[64], p2 = gn[128];

    const int rp = t & 1;
    bf16x8 aF[4];
#pragma unroll
    for (int kk = 0; kk < 4; ++kk)
      aF[kk] = *(const bf16x8*)&s_b16[rp][lm * 136 + kk * 32 + lg * 8];

    f32x4 aU = {0.f, 0.f, 0.f, 0.f};
    f32x4 aR = {0.f, 0.f, 0.f, 0.f};
    f32x4 aC = {0.f, 0.f, 0.f, 0.f};
#pragma unroll
    for (int kk = 0; kk < 4; ++kk) {
      aU = __builtin_amdgcn_mfma_f32_16x16x32_bf16(aF[kk], bu[kk].v, aU, 0, 0, 0);
      aR = __builtin_amdgcn_mfma_f32_16x16x32_bf16(aF[kk], br[kk].v, aR, 0, 0, 0);
      aC = __builtin_amdgcn_mfma_f32_16x16x32_bf16(aF[kk], bc[kk].v, aC, 0, 0, 0);
    }

    const float gu[4] = { lo_bf(q0.x), hi_bf(q0.x), lo_bf(q0.y), hi_bf(q0.y) };
    const float gr[4] = { lo_bf(q1.x), hi_bf(q1.x), lo_bf(q1.y), hi_bf(q1.y) };
    const float gc[4] = { lo_bf(q2.x), hi_bf(q2.x), lo_bf(q2.y), hi_bf(q2.y) };

#pragma unroll
    for (int i = 0; i < 4; ++i) {
      const int row = lg * 4 + i;
      float u = sigm(aU[i] + gu[i]);
      float r = sigm(aR[i] + gr[i]);
      float c = tanh_f(gc[i] + r * aC[i]);
      float at = a_lds[t * 16 + row];
      float mt = m_lds[row * T_LEN + t];
      float so = sreg[i];
      float uu = at * u;
      float sn = so + uu * (c - so);       // (1-u_)*s + u_*c
      float sf = so + mt * (sn - so);      // mask blend
      sreg[i] = sf;
      s_b16[rp ^ 1][row * 136 + col] = (bf16_t)sf;
    }

    q0 = p0; q1 = p1; q2 = p2;
    BAR_LDS();
  };

#pragma unroll 1
  for (int t = 0; t < T_LEN; t += 2) {
    step(t,     c0, c1, c2);
    step(t + 1, d0, d1, d2);
  }

  // Write final state straight from registers
#pragma unroll
  for (int i = 0; i < 4; ++i) {
    const int row = lg * 4 + i;
    out[(R0 + row) * 128 + col] = sreg[i];
  }
}

// ---------------------------------------------------------------------------
extern "C" void kernel_launch(void* const* d_in, const int* in_sizes, int n_in,
                              void* d_out, int out_size, void* d_ws, size_t ws_size,
                              hipStream_t stream)
{
  const float* x    = (const float*)d_in[0];
  const float* st   = (const float*)d_in[1];
  const float* att  = (const float*)d_in[2];
  const float* mask = (const float*)d_in[3];
  // d_in[4] = max_len (unused; shapes hard-coded)
  const float* Wau  = (const float*)d_in[5];
  const float* bau  = (const float*)d_in[6];
  const float* Wbu  = (const float*)d_in[7];
  const float* War  = (const float*)d_in[8];
  const float* bar  = (const float*)d_in[9];
  const float* Wbr  = (const float*)d_in[10];
  const float* Wac  = (const float*)d_in[11];
  const float* bac  = (const float*)d_in[12];
  const float* Wbc  = (const float*)d_in[13];

  uint2* G = (uint2*)d_ws;  // 12800*8*192*8 = 157,286,400 bytes

  k1_gates<<<dim3(1280), dim3(512), 0, stream>>>(x, Wau, bau, War, bar, Wac, bac, G);
  k2_scan<<<dim3(64), dim3(512), 0, stream>>>(st, att, mask, Wbu, Wbr, Wbc, G,
                                              (float*)d_out);
}

// Round 3
// 369.242 us; speedup vs baseline: 1.3956x; 1.0934x over previous
//
#include <hip/hip_runtime.h>
#include <stdint.h>

#define T_LEN 200
#define B_SZ  1024
#define D_DIM 128
#define NTILE (T_LEN * B_SZ / 16)   // 12800 M-tiles of 16 batch-rows
#define LOG2E 1.44269504088896340736f

typedef __bf16 bf16_t;
typedef __bf16 bf16x8 __attribute__((ext_vector_type(8)));
typedef float  f32x4  __attribute__((ext_vector_type(4)));
typedef float  f32x8  __attribute__((ext_vector_type(8)));

union BF8 { bf16x8 v; bf16_t e[8]; };
union F8V { f32x8 v; float4 q[2]; };

// RNE fp32->bf16 pack of two values into one dword
__device__ inline uint32_t pk_bf16(float a, float b) {
  uint32_t ua = __float_as_uint(a), ub = __float_as_uint(b);
  ua += 0x7fffu + ((ua >> 16) & 1u);
  ub += 0x7fffu + ((ub >> 16) & 1u);
  return (ua >> 16) | (ub & 0xffff0000u);
}
__device__ inline float lo_bf(uint32_t x) { return __uint_as_float(x << 16); }
__device__ inline float hi_bf(uint32_t x) { return __uint_as_float(x & 0xffff0000u); }
__device__ inline float rcp_f(float x)  { return __builtin_amdgcn_rcpf(x); }

// LDS-only barrier: wait LDS ops, but leave global loads (vmcnt) in flight.
#define BAR_LDS() asm volatile("s_waitcnt lgkmcnt(0)\n\ts_barrier" ::: "memory")

// ---------------------------------------------------------------------------
// K1: G[t,b,:] = log-scaled (x[t,b,:] @ [Wau|War|Wac] + [bau|bar|bac]), bf16,
// pre-swizzled to the (tile, wave, lane) C-layout K2 consumes.
// u,r pre-activations scaled by log2e; c by 2*log2e (so K2 uses exp2 directly).
// 2-deep software pipeline on the x loads.
// ---------------------------------------------------------------------------
__global__ __launch_bounds__(512, 2) void k1_gates(
    const float* __restrict__ x,
    const float* __restrict__ Wau, const float* __restrict__ bau,
    const float* __restrict__ War, const float* __restrict__ bar,
    const float* __restrict__ Wac, const float* __restrict__ bac,
    uint2* __restrict__ G)
{
  const int tid = threadIdx.x;
  const int w  = tid >> 6;
  const int l  = tid & 63;
  const int lm = l & 15;
  const int lg = l >> 4;
  const int col = w * 16 + lm;

  BF8 bu[4], br[4], bc[4];
#pragma unroll
  for (int kk = 0; kk < 4; ++kk) {
#pragma unroll
    for (int j = 0; j < 8; ++j) {
      int k = kk * 32 + lg * 8 + j;
      bu[kk].e[j] = (bf16_t)(Wau[k * 128 + col] * LOG2E);
      br[kk].e[j] = (bf16_t)(War[k * 128 + col] * LOG2E);
      bc[kk].e[j] = (bf16_t)(Wac[k * 128 + col] * (2.0f * LOG2E));
    }
  }
  const float b_u = bau[col] * LOG2E;
  const float b_r = bar[col] * LOG2E;
  const float b_c = bac[col] * (2.0f * LOG2E);

  const int stride = gridDim.x;
  int tau = blockIdx.x;

  float4 cur[8];
  {
    const float* xp = x + (size_t)((tau >> 6) * B_SZ + (tau & 63) * 16 + lm) * D_DIM + lg * 8;
#pragma unroll
    for (int kk = 0; kk < 4; ++kk) {
      cur[2 * kk]     = *(const float4*)(xp + kk * 32);
      cur[2 * kk + 1] = *(const float4*)(xp + kk * 32 + 4);
    }
  }

#pragma unroll 1
  while (tau < NTILE) {
    const int tn = tau + stride;
    float4 nxt[8];
    if (tn < NTILE) {
      const float* xp = x + (size_t)((tn >> 6) * B_SZ + (tn & 63) * 16 + lm) * D_DIM + lg * 8;
#pragma unroll
      for (int kk = 0; kk < 4; ++kk) {
        nxt[2 * kk]     = *(const float4*)(xp + kk * 32);
        nxt[2 * kk + 1] = *(const float4*)(xp + kk * 32 + 4);
      }
    }

    bf16x8 aF[4];
#pragma unroll
    for (int kk = 0; kk < 4; ++kk) {
      F8V t8;
      t8.q[0] = cur[2 * kk];
      t8.q[1] = cur[2 * kk + 1];
      aF[kk] = __builtin_convertvector(t8.v, bf16x8);
    }

    f32x4 aU = {b_u, b_u, b_u, b_u};
    f32x4 aR = {b_r, b_r, b_r, b_r};
    f32x4 aC = {b_c, b_c, b_c, b_c};
#pragma unroll
    for (int kk = 0; kk < 4; ++kk) {
      aU = __builtin_amdgcn_mfma_f32_16x16x32_bf16(aF[kk], bu[kk].v, aU, 0, 0, 0);
      aR = __builtin_amdgcn_mfma_f32_16x16x32_bf16(aF[kk], br[kk].v, aR, 0, 0, 0);
      aC = __builtin_amdgcn_mfma_f32_16x16x32_bf16(aF[kk], bc[kk].v, aC, 0, 0, 0);
    }

    uint2* gp = G + ((size_t)tau * 8 + w) * 192 + l;
    gp[0]   = make_uint2(pk_bf16(aU[0], aU[1]), pk_bf16(aU[2], aU[3]));
    gp[64]  = make_uint2(pk_bf16(aR[0], aR[1]), pk_bf16(aR[2], aR[3]));
    gp[128] = make_uint2(pk_bf16(aC[0], aC[1]), pk_bf16(aC[2], aC[3]));

#pragma unroll
    for (int j = 0; j < 8; ++j) cur[j] = nxt[j];
    tau = tn;
  }
}

// ---------------------------------------------------------------------------
// K2: sequential scan, 64 blocks x 512 threads. fp32 state in registers;
// bf16 state ping-pong in LDS with LINEAR-LANE layout (element (row,k) at
// halfword idx (k>>5)*512 + ((k>>3)&3)*128 + row*8 + (k&7)) so the A-fragment
// reads are ds_read_b128 at 16*lane -> conflict-free. MFMA accumulators
// init'd directly from the prefetched G gates; epilogue uses exp2/rcp only.
// ---------------------------------------------------------------------------
__global__ __launch_bounds__(512) void k2_scan(
    const float* __restrict__ state,
    const float* __restrict__ att,
    const float* __restrict__ mask,
    const float* __restrict__ Wbu, const float* __restrict__ Wbr,
    const float* __restrict__ Wbc,
    const uint2* __restrict__ G,
    float* __restrict__ out)
{
  __shared__ bf16_t sb[2 * 2048];        // ping-pong bf16 state, linear-lane layout
  __shared__ float  am_lds[T_LEN * 16];  // att*mask fused, [t][row]

  const int tid = threadIdx.x;
  const int w  = tid >> 6;
  const int l  = tid & 63;
  const int lm = l & 15;
  const int lg = l >> 4;
  const int bb = blockIdx.x;
  const int R0 = bb * 16;
  const int col = w * 16 + lm;

  // Recurrent-weight B-fragments, pre-scaled (u,r: log2e; c: 2*log2e)
  BF8 bu[4], br[4], bc[4];
#pragma unroll
  for (int kk = 0; kk < 4; ++kk) {
#pragma unroll
    for (int j = 0; j < 8; ++j) {
      int k = kk * 32 + lg * 8 + j;
      bu[kk].e[j] = (bf16_t)(Wbu[k * 128 + col] * LOG2E);
      br[kk].e[j] = (bf16_t)(Wbr[k * 128 + col] * LOG2E);
      bc[kk].e[j] = (bf16_t)(Wbc[k * 128 + col] * (2.0f * LOG2E));
    }
  }

  // Fused att*mask preload
  for (int idx = tid; idx < T_LEN * 16; idx += 512) {
    int t = idx >> 4, row = idx & 15;
    am_lds[idx] = att[t * B_SZ + R0 + row] * mask[(R0 + row) * T_LEN + t];
  }

  // fp32 state in registers: lane owns (row = lg*4+i, col)
  float sreg[4];
#pragma unroll
  for (int i = 0; i < 4; ++i)
    sreg[i] = state[(R0 + lg * 4 + i) * 128 + col];

  // bf16 state into buffer 0, linear-lane layout
  for (int idx = tid; idx < 2048; idx += 512) {
    int row = idx >> 7, k = idx & 127;
    sb[(k >> 5) * 512 + ((k >> 3) & 3) * 128 + row * 8 + (k & 7)] =
        (bf16_t)state[(R0 + row) * 128 + k];
  }

  // G base for this (block, wave, lane); per-t stride = 64*8*192 = 98304
  const uint2* gB = G + ((size_t)bb * 8 + w) * 192 + l;
  uint2 c0 = gB[0], c1 = gB[64], c2 = gB[128];
  const uint2* g1 = gB + 98304;
  uint2 d0 = g1[0], d1 = g1[64], d2 = g1[128];

  // Write-index base (halfwords): element (row=lg*4+i, k=col), +8 per i
  const int wbase = (w >> 1) * 512 + ((((w & 1) << 1) | (lm >> 3)) * 128)
                  + lg * 32 + (lm & 7);

  __syncthreads();   // full drain once before the scan

  auto step = [&](int t, uint2& q0, uint2& q1, uint2& q2) {
    // prefetch t+2's gates (stay in flight across the LDS-only barrier)
    const int tp = (t + 2 < T_LEN) ? t + 2 : T_LEN - 1;
    const uint2* gn = gB + (size_t)tp * 98304;
    uint2 p0 = gn[0], p1 = gn[64], p2 = gn[128];

    const int rp = t & 1;
    const bf16_t* rbuf = sb + rp * 2048;
    bf16x8 aF[4];
#pragma unroll
    for (int kk = 0; kk < 4; ++kk)
      aF[kk] = *(const bf16x8*)&rbuf[kk * 512 + 8 * l];

    // Accumulators init'd with the x-side gate pre-activations (u, r)
    f32x4 aU = { lo_bf(q0.x), hi_bf(q0.x), lo_bf(q0.y), hi_bf(q0.y) };
    f32x4 aR = { lo_bf(q1.x), hi_bf(q1.x), lo_bf(q1.y), hi_bf(q1.y) };
    f32x4 aC = { 0.f, 0.f, 0.f, 0.f };
    const float gc[4] = { lo_bf(q2.x), hi_bf(q2.x), lo_bf(q2.y), hi_bf(q2.y) };

#pragma unroll
    for (int kk = 0; kk < 4; ++kk) {
      aU = __builtin_amdgcn_mfma_f32_16x16x32_bf16(aF[kk], bu[kk].v, aU, 0, 0, 0);
      aR = __builtin_amdgcn_mfma_f32_16x16x32_bf16(aF[kk], br[kk].v, aR, 0, 0, 0);
      aC = __builtin_amdgcn_mfma_f32_16x16x32_bf16(aF[kk], bc[kk].v, aC, 0, 0, 0);
    }

    union { float4 v; float e[4]; } amu;
    amu.v = *(const float4*)&am_lds[t * 16 + lg * 4];

    bf16_t* wbuf = sb + (rp ^ 1) * 2048;
#pragma unroll
    for (int i = 0; i < 4; ++i) {
      // u = sigmoid(zu), zu pre-scaled by log2e -> rcp(1+exp2(-zu'))
      float u  = rcp_f(1.0f + __builtin_amdgcn_exp2f(-aU[i]));
      float r  = rcp_f(1.0f + __builtin_amdgcn_exp2f(-aR[i]));
      // c = tanh(zc), zc' = 2*log2e*zc = gc + r*aC
      float wc = fmaf(r, aC[i], gc[i]);
      float cg = fmaf(-2.0f, rcp_f(__builtin_amdgcn_exp2f(wc) + 1.0f), 1.0f);
      float uu = amu.e[i] * u;                   // (att*mask)*u
      float sf = fmaf(uu, cg - sreg[i], sreg[i]);
      sreg[i] = sf;
      wbuf[wbase + 8 * i] = (bf16_t)sf;
    }

    q0 = p0; q1 = p1; q2 = p2;
    BAR_LDS();
  };

#pragma unroll 1
  for (int t = 0; t < T_LEN; t += 2) {
    step(t,     c0, c1, c2);
    step(t + 1, d0, d1, d2);
  }

#pragma unroll
  for (int i = 0; i < 4; ++i)
    out[(R0 + lg * 4 + i) * 128 + col] = sreg[i];
}

// ---------------------------------------------------------------------------
extern "C" void kernel_launch(void* const* d_in, const int* in_sizes, int n_in,
                              void* d_out, int out_size, void* d_ws, size_t ws_size,
                              hipStream_t stream)
{
  const float* x    = (const float*)d_in[0];
  const float* st   = (const float*)d_in[1];
  const float* att  = (const float*)d_in[2];
  const float* mask = (const float*)d_in[3];
  // d_in[4] = max_len (unused; shapes hard-coded)
  const float* Wau  = (const float*)d_in[5];
  const float* bau  = (const float*)d_in[6];
  const float* Wbu  = (const float*)d_in[7];
  const float* War  = (const float*)d_in[8];
  const float* bar  = (const float*)d_in[9];
  const float* Wbr  = (const float*)d_in[10];
  const float* Wac  = (const float*)d_in[11];
  const float* bac  = (const float*)d_in[12];
  const float* Wbc  = (const float*)d_in[13];

  uint2* G = (uint2*)d_ws;  // 12800*8*192*8 = 157,286,400 bytes

  k1_gates<<<dim3(1280), dim3(512), 0, stream>>>(x, Wau, bau, War, bar, Wac, bac, G);
  k2_scan<<<dim3(64), dim3(512), 0, stream>>>(st, att, mask, Wbu, Wbr, Wbc, G,
                                              (float*)d_out);
}

// Round 5
// 313.736 us; speedup vs baseline: 1.6425x; 1.1769x over previous
//
#include <hip/hip_runtime.h>
#include <stdint.h>

#define T_LEN 200
#define B_SZ  1024
#define D_DIM 128
#define LOG2E 1.44269504088896340736f

typedef __bf16 bf16_t;
typedef __bf16 bf16x8 __attribute__((ext_vector_type(8)));
typedef float  f32x4  __attribute__((ext_vector_type(4)));

union BF8 { bf16x8 v; bf16_t e[8]; };

// RNE fp32->bf16 pack of two values into one dword
__device__ inline uint32_t pk_bf16(float a, float b) {
  uint32_t ua = __float_as_uint(a), ub = __float_as_uint(b);
  ua += 0x7fffu + ((ua >> 16) & 1u);
  ub += 0x7fffu + ((ub >> 16) & 1u);
  return (ua >> 16) | (ub & 0xffff0000u);
}
__device__ inline float rcp_f(float x) { return __builtin_amdgcn_rcpf(x); }

// LDS-only barrier: wait LDS ops, leave global loads (vmcnt) in flight.
#define BAR_LDS() asm volatile("s_waitcnt lgkmcnt(0)\n\ts_barrier" ::: "memory")

// ---------------------------------------------------------------------------
// Fused AUGRU scan. 64 blocks x 512 threads; block bb owns batch rows
// [16*bb, 16*bb+16). Per step: x-side gates (12 MFMAs) + state-side (12 MFMAs)
// computed in-kernel; x staged global->reg (depth-3) ->bf16 LDS; state bf16
// ping-pong in LDS. Frag-linear LDS layout: element (row,k) at HALFWORD index
// (k>>5)*512 + ((k>>3)&3)*128 + row*8 + (k&7)  ->  lane l's kk-fragment is
// halfwords [kk*512 + 8*l, +8) (16 contiguous bytes; conflict-free b128).
// ---------------------------------------------------------------------------
__global__ __launch_bounds__(512, 2) void augru_fused(
    const float* __restrict__ x,
    const float* __restrict__ state,
    const float* __restrict__ att,
    const float* __restrict__ mask,
    const float* __restrict__ Wau, const float* __restrict__ bau,
    const float* __restrict__ Wbu,
    const float* __restrict__ War, const float* __restrict__ bar,
    const float* __restrict__ Wbr,
    const float* __restrict__ Wac, const float* __restrict__ bac,
    const float* __restrict__ Wbc,
    float* __restrict__ out)
{
  __shared__ bf16_t xb[2][2048];         // x tile ping-pong (bf16, frag-linear)
  __shared__ bf16_t sb[2][2048];         // state ping-pong (bf16, frag-linear)
  __shared__ float  am_lds[T_LEN * 16];  // att*mask fused, [t][row]

  const int tid = threadIdx.x;
  const int w  = tid >> 6;
  const int l  = tid & 63;
  const int lm = l & 15;
  const int lg = l >> 4;
  const int bb = blockIdx.x;
  const int R0 = bb * 16;
  const int col = w * 16 + lm;

  // --- weight B-fragments in registers (pre-scaled: u,r by log2e; c by 2log2e)
  BF8 xu[4], xr[4], xc[4];   // x-side  (Wau, War, Wac)
  BF8 su[4], sr[4], sc[4];   // state-side (Wbu, Wbr, Wbc)
#pragma unroll
  for (int kk = 0; kk < 4; ++kk) {
#pragma unroll
    for (int j = 0; j < 8; ++j) {
      int k = kk * 32 + lg * 8 + j;
      xu[kk].e[j] = (bf16_t)(Wau[k * 128 + col] * LOG2E);
      xr[kk].e[j] = (bf16_t)(War[k * 128 + col] * LOG2E);
      xc[kk].e[j] = (bf16_t)(Wac[k * 128 + col] * (2.0f * LOG2E));
      su[kk].e[j] = (bf16_t)(Wbu[k * 128 + col] * LOG2E);
      sr[kk].e[j] = (bf16_t)(Wbr[k * 128 + col] * LOG2E);
      sc[kk].e[j] = (bf16_t)(Wbc[k * 128 + col] * (2.0f * LOG2E));
    }
  }
  const float b_u = bau[col] * LOG2E;
  const float b_r = bar[col] * LOG2E;
  const float b_c = bac[col] * (2.0f * LOG2E);

  // --- att*mask preload
  for (int idx = tid; idx < T_LEN * 16; idx += 512) {
    int t = idx >> 4, row = idx & 15;
    am_lds[idx] = att[t * B_SZ + R0 + row] * mask[(R0 + row) * T_LEN + t];
  }

  // --- fp32 state in registers: lane owns (row = lg*4+i, col)
  float sreg[4];
#pragma unroll
  for (int i = 0; i < 4; ++i)
    sreg[i] = state[(R0 + lg * 4 + i) * 128 + col];

  // state bf16 into buffer 0, frag-linear layout
  for (int idx = tid; idx < 2048; idx += 512) {
    int row = idx >> 7, k = idx & 127;
    sb[0][(k >> 5) * 512 + ((k >> 3) & 3) * 128 + row * 8 + (k & 7)] =
        (bf16_t)state[(R0 + row) * 128 + k];
  }

  // --- x staging: thread tid stages row=tid&15, float4 chunk c=tid>>4 (0..31)
  const int srow = tid & 15;
  const int sc4  = tid >> 4;                     // 16B chunk index within row
  const int stg_pos = (sc4 >> 3) * 512 + ((sc4 >> 1) & 3) * 128 + srow * 8
                    + (sc4 & 1) * 4;             // halfword index (8B aligned)
  const float* xrow = x + (size_t)(R0 + srow) * 128 + sc4 * 4;
  const size_t xstep = (size_t)B_SZ * 128;       // per-t stride

  // stage x(0) into xb[0]
  {
    float4 v = *(const float4*)(xrow);
    uint2 p; p.x = pk_bf16(v.x, v.y); p.y = pk_bf16(v.z, v.w);
    *(uint2*)&xb[0][stg_pos] = p;
  }
  // prefetch x(1..3) into registers (depth-3)
  float4 xq0 = *(const float4*)(xrow + 1 * xstep);
  float4 xq1 = *(const float4*)(xrow + 2 * xstep);
  float4 xq2 = *(const float4*)(xrow + 3 * xstep);

  __syncthreads();   // full drain once before the scan

  auto step = [&](int t) {
    const int rp = t & 1;

    // stage x(t+1) from the oldest prefetch reg into xb[(t+1)&1]
    {
      uint2 p; p.x = pk_bf16(xq0.x, xq0.y); p.y = pk_bf16(xq0.z, xq0.w);
      *(uint2*)&xb[rp ^ 1][stg_pos] = p;
    }
    xq0 = xq1; xq1 = xq2;
    int tl = t + 4; if (tl > T_LEN - 1) tl = T_LEN - 1;
    xq2 = *(const float4*)(xrow + (size_t)tl * xstep);

    // fragment reads (conflict-free contiguous b128) — HALFWORD index kk*512+8l
    bf16x8 ax[4], as_[4];
#pragma unroll
    for (int kk = 0; kk < 4; ++kk) {
      ax[kk]  = *(const bf16x8*)&xb[rp][kk * 512 + 8 * l];
      as_[kk] = *(const bf16x8*)&sb[rp][kk * 512 + 8 * l];
    }

    // x-side gates (init with bias), state-side into separate accumulators
    f32x4 aU = {b_u, b_u, b_u, b_u};
    f32x4 aR = {b_r, b_r, b_r, b_r};
    f32x4 aC = {b_c, b_c, b_c, b_c};
    f32x4 bU = {0.f, 0.f, 0.f, 0.f};
    f32x4 bR = {0.f, 0.f, 0.f, 0.f};
    f32x4 bC = {0.f, 0.f, 0.f, 0.f};
#pragma unroll
    for (int kk = 0; kk < 4; ++kk) {
      aU = __builtin_amdgcn_mfma_f32_16x16x32_bf16(ax[kk],  xu[kk].v, aU, 0, 0, 0);
      bU = __builtin_amdgcn_mfma_f32_16x16x32_bf16(as_[kk], su[kk].v, bU, 0, 0, 0);
      aR = __builtin_amdgcn_mfma_f32_16x16x32_bf16(ax[kk],  xr[kk].v, aR, 0, 0, 0);
      bR = __builtin_amdgcn_mfma_f32_16x16x32_bf16(as_[kk], sr[kk].v, bR, 0, 0, 0);
      aC = __builtin_amdgcn_mfma_f32_16x16x32_bf16(ax[kk],  xc[kk].v, aC, 0, 0, 0);
      bC = __builtin_amdgcn_mfma_f32_16x16x32_bf16(as_[kk], sc[kk].v, bC, 0, 0, 0);
    }

    union { float4 v; float e[4]; } amu;
    amu.v = *(const float4*)&am_lds[t * 16 + lg * 4];

    bf16_t* wbuf = sb[rp ^ 1];
    const int wbase = (col >> 5) * 512 + ((col >> 3) & 3) * 128 + lg * 32
                    + (col & 7);   // halfword pos of (row=lg*4, k=col)
#pragma unroll
    for (int i = 0; i < 4; ++i) {
      float zu = aU[i] + bU[i];
      float zr = aR[i] + bR[i];
      float u  = rcp_f(1.0f + __builtin_amdgcn_exp2f(-zu));
      float r  = rcp_f(1.0f + __builtin_amdgcn_exp2f(-zr));
      float wc = fmaf(r, bC[i], aC[i]);
      float cg = fmaf(-2.0f, rcp_f(__builtin_amdgcn_exp2f(wc) + 1.0f), 1.0f);
      float sf = fmaf(amu.e[i] * u, cg - sreg[i], sreg[i]);
      sreg[i] = sf;
      wbuf[wbase + 8 * i] = (bf16_t)sf;
    }

    BAR_LDS();
  };

#pragma unroll 1
  for (int t = 0; t < T_LEN; t += 2) {
    step(t);
    step(t + 1);
  }

#pragma unroll
  for (int i = 0; i < 4; ++i)
    out[(R0 + lg * 4 + i) * 128 + col] = sreg[i];
}

// ---------------------------------------------------------------------------
extern "C" void kernel_launch(void* const* d_in, const int* in_sizes, int n_in,
                              void* d_out, int out_size, void* d_ws, size_t ws_size,
                              hipStream_t stream)
{
  const float* x    = (const float*)d_in[0];
  const float* st   = (const float*)d_in[1];
  const float* att  = (const float*)d_in[2];
  const float* mask = (const float*)d_in[3];
  // d_in[4] = max_len (unused; shapes hard-coded)
  const float* Wau  = (const float*)d_in[5];
  const float* bau  = (const float*)d_in[6];
  const float* Wbu  = (const float*)d_in[7];
  const float* War  = (const float*)d_in[8];
  const float* bar  = (const float*)d_in[9];
  const float* Wbr  = (const float*)d_in[10];
  const float* Wac  = (const float*)d_in[11];
  const float* bac  = (const float*)d_in[12];
  const float* Wbc  = (const float*)d_in[13];

  (void)d_ws; (void)ws_size;

  augru_fused<<<dim3(64), dim3(512), 0, stream>>>(
      x, st, att, mask, Wau, bau, Wbu, War, bar, Wbr, Wac, bac, Wbc,
      (float*)d_out);
}

// Round 6
// 309.221 us; speedup vs baseline: 1.6665x; 1.0146x over previous
//
#include <hip/hip_runtime.h>
#include <stdint.h>

#define T_LEN 200
#define B_SZ  1024
#define D_DIM 128
#define LOG2E 1.44269504088896340736f

typedef __bf16 bf16_t;
typedef __bf16 bf16x8 __attribute__((ext_vector_type(8)));
typedef float  f32x4  __attribute__((ext_vector_type(4)));

union BF8 { bf16x8 v; bf16_t e[8]; };

// RNE fp32->bf16 pack of two values into one dword
__device__ inline uint32_t pk_bf16(float a, float b) {
  uint32_t ua = __float_as_uint(a), ub = __float_as_uint(b);
  ua += 0x7fffu + ((ua >> 16) & 1u);
  ub += 0x7fffu + ((ub >> 16) & 1u);
  return (ua >> 16) | (ub & 0xffff0000u);
}
__device__ inline float rcp_f(float x) { return __builtin_amdgcn_rcpf(x); }

// LDS-only barrier: wait LDS ops, leave global loads (vmcnt) in flight.
#define BAR_LDS() asm volatile("s_waitcnt lgkmcnt(0)\n\ts_barrier" ::: "memory")

// ---------------------------------------------------------------------------
// Fused AUGRU scan, software-pipelined x-side.
// 64 blocks x 512 threads; block bb owns batch rows [16*bb, 16*bb+16).
// At step t: stage x(t+2)->LDS, compute x-gates(t+1) into REGISTERS (off the
// critical path), state-side MFMAs for t chain onto x-gate regs from t-1
// (C-operand init), epilogue -> state write (XOR-swizzled to kill bank
// conflicts). One LDS-only barrier per step.
// LDS layouts (halfword index):
//   xb: slot(row,k) = (k>>3)*128 + row*8 + (k&7)           (frag = 8*l)
//   sb: slot(row,k) = (k>>3)*128 + (row^(2*((k>>3)&1)))*8 + (k&7)
//       reader frag = 8*(l ^ 2*(lg&1)); writer slots wbase + 8*(i^psi)
// ---------------------------------------------------------------------------
__global__ __launch_bounds__(512, 2) void augru_fused(
    const float* __restrict__ x,
    const float* __restrict__ state,
    const float* __restrict__ att,
    const float* __restrict__ mask,
    const float* __restrict__ Wau, const float* __restrict__ bau,
    const float* __restrict__ Wbu,
    const float* __restrict__ War, const float* __restrict__ bar,
    const float* __restrict__ Wbr,
    const float* __restrict__ Wac, const float* __restrict__ bac,
    const float* __restrict__ Wbc,
    float* __restrict__ out)
{
  __shared__ bf16_t xb[2][2048];         // x tiles (bf16, frag-linear)
  __shared__ bf16_t sb[2][2048];         // state ping-pong (bf16, swizzled)
  __shared__ float  am_lds[T_LEN * 16];  // att*mask fused, [t][row]

  const int tid = threadIdx.x;
  const int w  = tid >> 6;
  const int l  = tid & 63;
  const int lm = l & 15;
  const int lg = l >> 4;
  const int bb = blockIdx.x;
  const int R0 = bb * 16;
  const int col = w * 16 + lm;

  // --- weight B-fragments in registers (pre-scaled: u,r by log2e; c by 2log2e)
  BF8 xu[4], xr[4], xc[4];   // x-side  (Wau, War, Wac)
  BF8 su[4], sr[4], sc[4];   // state-side (Wbu, Wbr, Wbc)
#pragma unroll
  for (int kk = 0; kk < 4; ++kk) {
#pragma unroll
    for (int j = 0; j < 8; ++j) {
      int k = kk * 32 + lg * 8 + j;
      xu[kk].e[j] = (bf16_t)(Wau[k * 128 + col] * LOG2E);
      xr[kk].e[j] = (bf16_t)(War[k * 128 + col] * LOG2E);
      xc[kk].e[j] = (bf16_t)(Wac[k * 128 + col] * (2.0f * LOG2E));
      su[kk].e[j] = (bf16_t)(Wbu[k * 128 + col] * LOG2E);
      sr[kk].e[j] = (bf16_t)(Wbr[k * 128 + col] * LOG2E);
      sc[kk].e[j] = (bf16_t)(Wbc[k * 128 + col] * (2.0f * LOG2E));
    }
  }
  const float b_u = bau[col] * LOG2E;
  const float b_r = bar[col] * LOG2E;
  const float b_c = bac[col] * (2.0f * LOG2E);

  // --- att*mask preload
  for (int idx = tid; idx < T_LEN * 16; idx += 512) {
    int t = idx >> 4, row = idx & 15;
    am_lds[idx] = att[t * B_SZ + R0 + row] * mask[(R0 + row) * T_LEN + t];
  }

  // --- fp32 state in registers: lane owns (row = lg*4+i, col)
  float sreg[4];
#pragma unroll
  for (int i = 0; i < 4; ++i)
    sreg[i] = state[(R0 + lg * 4 + i) * 128 + col];

  // state bf16 into sb[0], swizzled layout
  for (int idx = tid; idx < 2048; idx += 512) {
    int row = idx >> 7, k = idx & 127;
    sb[0][(k >> 3) * 128 + (row ^ (2 * ((k >> 3) & 1))) * 8 + (k & 7)] =
        (bf16_t)state[(R0 + row) * 128 + k];
  }

  // --- x staging: thread tid stages row=tid&15, float4 chunk sc4=tid>>4
  const int srow = tid & 15;
  const int sc4  = tid >> 4;
  const int stg_pos = (sc4 >> 1) * 128 + srow * 8 + (sc4 & 1) * 4;  // halfwords
  const float* xrow = x + (size_t)(R0 + srow) * 128 + sc4 * 4;
  const size_t xstep = (size_t)B_SZ * 128;

  // prologue: stage x(0), x(1); register-prefetch x(2..4)
  {
    float4 v0 = *(const float4*)(xrow);
    float4 v1 = *(const float4*)(xrow + xstep);
    uint2 p0; p0.x = pk_bf16(v0.x, v0.y); p0.y = pk_bf16(v0.z, v0.w);
    uint2 p1; p1.x = pk_bf16(v1.x, v1.y); p1.y = pk_bf16(v1.z, v1.w);
    *(uint2*)&xb[0][stg_pos] = p0;
    *(uint2*)&xb[1][stg_pos] = p1;
  }
  float4 xq0 = *(const float4*)(xrow + 2 * xstep);
  float4 xq1 = *(const float4*)(xrow + 3 * xstep);
  float4 xq2 = *(const float4*)(xrow + 4 * xstep);

  __syncthreads();   // full drain once

  // x-gates(0) from xb[0] into registers
  f32x4 gU = {b_u, b_u, b_u, b_u};
  f32x4 gR = {b_r, b_r, b_r, b_r};
  f32x4 gC = {b_c, b_c, b_c, b_c};
  {
    bf16x8 ax[4];
#pragma unroll
    for (int kk = 0; kk < 4; ++kk)
      ax[kk] = *(const bf16x8*)&xb[0][kk * 512 + 8 * l];
#pragma unroll
    for (int kk = 0; kk < 4; ++kk) {
      gU = __builtin_amdgcn_mfma_f32_16x16x32_bf16(ax[kk], xu[kk].v, gU, 0, 0, 0);
      gR = __builtin_amdgcn_mfma_f32_16x16x32_bf16(ax[kk], xr[kk].v, gR, 0, 0, 0);
      gC = __builtin_amdgcn_mfma_f32_16x16x32_bf16(ax[kk], xc[kk].v, gC, 0, 0, 0);
    }
  }
  union F4 { float4 v; float e[4]; } amv;
  amv.v = *(const float4*)&am_lds[lg * 4];           // am(0)

  const int lx8   = 8 * (l ^ (2 * (lg & 1)));        // swizzled sb frag offset
  const int psi   = 2 * ((col >> 3) & 1);            // writer value permutation
  const int wbase = (col >> 3) * 128 + lg * 32 + (col & 7);

  BAR_LDS();   // protect xb[0] before step 0 overwrites it

  auto step = [&](int t) {
    const int rp = t & 1;

    // stage x(t+2) into xb[rp] (consumed at step t+1 after this step's barrier)
    {
      uint2 p; p.x = pk_bf16(xq0.x, xq0.y); p.y = pk_bf16(xq0.z, xq0.w);
      *(uint2*)&xb[rp][stg_pos] = p;
    }
    xq0 = xq1; xq1 = xq2;
    int tl = t + 5; if (tl > T_LEN - 1) tl = T_LEN - 1;
    xq2 = *(const float4*)(xrow + (size_t)tl * xstep);

    // fragment reads: x(t+1) (staged at t-1) and s(t)
    bf16x8 ax[4], as_[4];
#pragma unroll
    for (int kk = 0; kk < 4; ++kk) {
      ax[kk]  = *(const bf16x8*)&xb[rp ^ 1][kk * 512 + 8 * l];
      as_[kk] = *(const bf16x8*)&sb[rp][kk * 512 + lx8];
    }

    // state-side for t (chained onto x-gate regs) + x-side for t+1 (fresh)
    f32x4 aU = gU, aR = gR;
    f32x4 bC = {0.f, 0.f, 0.f, 0.f};
    f32x4 nU = {b_u, b_u, b_u, b_u};
    f32x4 nR = {b_r, b_r, b_r, b_r};
    f32x4 nC = {b_c, b_c, b_c, b_c};
#pragma unroll
    for (int kk = 0; kk < 4; ++kk) {
      aU = __builtin_amdgcn_mfma_f32_16x16x32_bf16(as_[kk], su[kk].v, aU, 0, 0, 0);
      nU = __builtin_amdgcn_mfma_f32_16x16x32_bf16(ax[kk],  xu[kk].v, nU, 0, 0, 0);
      aR = __builtin_amdgcn_mfma_f32_16x16x32_bf16(as_[kk], sr[kk].v, aR, 0, 0, 0);
      nR = __builtin_amdgcn_mfma_f32_16x16x32_bf16(ax[kk],  xr[kk].v, nR, 0, 0, 0);
      bC = __builtin_amdgcn_mfma_f32_16x16x32_bf16(as_[kk], sc[kk].v, bC, 0, 0, 0);
      nC = __builtin_amdgcn_mfma_f32_16x16x32_bf16(ax[kk],  xc[kk].v, nC, 0, 0, 0);
    }

    bf16_t* wbuf = sb[rp ^ 1];
#pragma unroll
    for (int i = 0; i < 4; ++i) {
      float u  = rcp_f(1.0f + __builtin_amdgcn_exp2f(-aU[i]));
      float r  = rcp_f(1.0f + __builtin_amdgcn_exp2f(-aR[i]));
      float wc = fmaf(r, bC[i], gC[i]);
      float cg = fmaf(-2.0f, rcp_f(__builtin_amdgcn_exp2f(wc) + 1.0f), 1.0f);
      float sf = fmaf(amv.e[i] * u, cg - sreg[i], sreg[i]);
      sreg[i] = sf;
      wbuf[wbase + 8 * (i ^ psi)] = (bf16_t)sf;
    }

    // rotate pipelined registers; prefetch am(t+1)
    gU = nU; gR = nR; gC = nC;
    int ta = t + 1; if (ta > T_LEN - 1) ta = T_LEN - 1;
    amv.v = *(const float4*)&am_lds[ta * 16 + lg * 4];

    BAR_LDS();
  };

#pragma unroll 1
  for (int t = 0; t < T_LEN; t += 2) {
    step(t);
    step(t + 1);
  }

#pragma unroll
  for (int i = 0; i < 4; ++i)
    out[(R0 + lg * 4 + i) * 128 + col] = sreg[i];
}

// ---------------------------------------------------------------------------
extern "C" void kernel_launch(void* const* d_in, const int* in_sizes, int n_in,
                              void* d_out, int out_size, void* d_ws, size_t ws_size,
                              hipStream_t stream)
{
  const float* x    = (const float*)d_in[0];
  const float* st   = (const float*)d_in[1];
  const float* att  = (const float*)d_in[2];
  const float* mask = (const float*)d_in[3];
  // d_in[4] = max_len (unused; shapes hard-coded)
  const float* Wau  = (const float*)d_in[5];
  const float* bau  = (const float*)d_in[6];
  const float* Wbu  = (const float*)d_in[7];
  const float* War  = (const float*)d_in[8];
  const float* bar  = (const float*)d_in[9];
  const float* Wbr  = (const float*)d_in[10];
  const float* Wac  = (const float*)d_in[11];
  const float* bac  = (const float*)d_in[12];
  const float* Wbc  = (const float*)d_in[13];

  (void)d_ws; (void)ws_size;

  augru_fused<<<dim3(64), dim3(512), 0, stream>>>(
      x, st, att, mask, Wau, bau, Wbu, War, bar, Wbr, Wac, bac, Wbc,
      (float*)d_out);
}